// Round 5
// baseline (11743.288 us; speedup 1.0000x reference)
//
#include <hip/hip_runtime.h>
#include <hip/hip_bf16.h>

// Problem constants (fixed by setup_inputs)
#define B_  2
#define C_  256
#define H_  64
#define W_  128
#define N_  (H_ * W_)   // 8192
#define K_  32          // top-k
#define CK  48          // stage-1 candidate count
#define TN  64          // n-rows per block
#define TM  64          // m-cols per tile
#define CP  264         // padded C pitch (bf16 elems)

typedef short  short8  __attribute__((ext_vector_type(8)));
typedef float  floatx4 __attribute__((ext_vector_type(4)));

__device__ __forceinline__ float b2f(ushort u) {
    unsigned x = ((unsigned)u) << 16; float f; __builtin_memcpy(&f, &x, 4); return f;
}
__device__ __forceinline__ ushort f2b(float f) {   // truncate (weakly monotone)
    unsigned x; __builtin_memcpy(&x, &f, 4); return (ushort)(x >> 16);
}

// ---------------------------------------------------------------------------
// Kernel 1: prep. fp32 [B][C][N] -> bf16 [B][N][C] (both maps) + fp32 [B][N][C] (f2)
// ---------------------------------------------------------------------------
__global__ void raft_prep_kernel(const float* __restrict__ f1,
                                 const float* __restrict__ f2,
                                 ushort* __restrict__ f1T,
                                 ushort* __restrict__ f2T,
                                 float* __restrict__ f2Tf) {
    __shared__ float tile[32][33];
    const int nt = blockIdx.x;          // N/32
    const int ct = blockIdx.y;          // C/32
    const int z  = blockIdx.z;          // b*2 + which
    const int b  = z >> 1;
    const float* __restrict__ src = (z & 1) ? f2 : f1;
    ushort* __restrict__ dstB     = (z & 1) ? f2T : f1T;
    const int tx = threadIdx.x;         // 0..31
    const int ty = threadIdx.y;         // 0..7

    #pragma unroll
    for (int i = 0; i < 4; ++i) {
        const int cl = ty * 4 + i;
        tile[cl][tx] = src[((size_t)b * C_ + (ct * 32 + cl)) * N_ + (nt * 32 + tx)];
    }
    __syncthreads();
    #pragma unroll
    for (int i = 0; i < 4; ++i) {
        const int nl = ty * 4 + i;
        const float v = tile[tx][nl];
        const size_t o = ((size_t)b * N_ + (nt * 32 + nl)) * C_ + (ct * 32 + tx);
        __hip_bfloat16 h = __float2bfloat16(v);        // RNE
        dstB[o] = *(const ushort*)&h;
        if (z & 1) f2Tf[o] = v;
    }
}

// ---------------------------------------------------------------------------
// Kernel 2: stage-1 — bf16 MFMA scores GEMM + streaming top-48 candidates
// grid: B_*(N_/TN) = 256 blocks, 256 threads (4 waves)
// ---------------------------------------------------------------------------
__launch_bounds__(256)
__global__ void raft_stage1_kernel(const ushort* __restrict__ f1T,
                                   const ushort* __restrict__ f2T,
                                   ushort* __restrict__ cand) {
    __shared__ ushort ABl[TM][CP];      // 33,792 B: A once, then B per m-tile
    __shared__ float  Sc[TN][68];       // 17,408 B: 64x64 score tile
    __shared__ ushort tv[TN][CK];       //  6,144 B: candidate values (bf16 bits)
    __shared__ ushort ti[TN][CK];       //  6,144 B: candidate indices

    const int bid  = blockIdx.x;
    const int b    = bid >> 7;
    const int nt0  = (bid & 127) * TN;
    const int tid  = threadIdx.x;
    const int w    = tid >> 6;
    const int lane = tid & 63;
    const int p    = lane & 15;
    const int q    = lane >> 4;

    const ushort* __restrict__ Aglob = f1T + (size_t)b * N_ * C_ + (size_t)nt0 * C_;
    const ushort* __restrict__ Bbase = f2T + (size_t)b * N_ * C_;

    // stage A tile (64 x 256)
    #pragma unroll
    for (int i = 0; i < 8; ++i) {
        const int id = tid + 256 * i;
        const int r  = id >> 5;
        const int cc = (id & 31) * 8;
        *(short8*)(&ABl[r][cc]) = *(const short8*)(Aglob + (size_t)r * C_ + cc);
    }
    for (int i = tid; i < TN * CK; i += 256) {
        tv[i / CK][i % CK] = 0xFF80;    // bf16 -inf
        ti[i / CK][i % CK] = 0;
    }
    __syncthreads();

    // preload A fragments
    short8 af[4][8];
    #pragma unroll
    for (int nt = 0; nt < 4; ++nt)
        #pragma unroll
        for (int ks = 0; ks < 8; ++ks)
            af[nt][ks] = *(const short8*)(&ABl[nt * 16 + p][ks * 32 + q * 8]);

    float thr = -INFINITY;

    for (int mt = 0; mt < N_ / TM; ++mt) {
        const int m0 = mt * TM;
        __syncthreads();

        #pragma unroll
        for (int i = 0; i < 8; ++i) {
            const int id = tid + 256 * i;
            const int r  = id >> 5;
            const int cc = (id & 31) * 8;
            *(short8*)(&ABl[r][cc]) =
                *(const short8*)(Bbase + (size_t)(m0 + r) * C_ + cc);
        }
        __syncthreads();

        floatx4 acc[4];
        #pragma unroll
        for (int nt = 0; nt < 4; ++nt) acc[nt] = (floatx4){0.f, 0.f, 0.f, 0.f};
        #pragma unroll
        for (int ks = 0; ks < 8; ++ks) {
            const short8 bf = *(const short8*)(&ABl[w * 16 + p][ks * 32 + q * 8]);
            #pragma unroll
            for (int nt = 0; nt < 4; ++nt)
                acc[nt] = __builtin_amdgcn_mfma_f32_16x16x32_bf16(af[nt][ks], bf, acc[nt], 0, 0, 0);
        }
        #pragma unroll
        for (int nt = 0; nt < 4; ++nt)
            #pragma unroll
            for (int r = 0; r < 4; ++r)
                Sc[nt * 16 + q * 4 + r][w * 16 + p] = acc[nt][r];
        __syncthreads();

        // streaming candidate scan: thread r owns row r
        if (tid < TN) {
            const int r = tid;
            for (int j4 = 0; j4 < TM / 4; ++j4) {
                const floatx4 v4 = *(const floatx4*)(&Sc[r][j4 * 4]);
                #pragma unroll
                for (int e = 0; e < 4; ++e) {
                    const float v = v4[e];
                    if (v > thr) {
                        const int m = m0 + j4 * 4 + e;
                        int pos = CK - 1;
                        while (pos > 0 && b2f(tv[r][pos - 1]) < v) {
                            tv[r][pos] = tv[r][pos - 1];
                            ti[r][pos] = ti[r][pos - 1];
                            --pos;
                        }
                        tv[r][pos] = f2b(v);
                        ti[r][pos] = (ushort)m;
                        thr = b2f(tv[r][CK - 1]);
                    }
                }
            }
        }
    }
    __syncthreads();

    // export candidate indices
    for (int i = tid; i < TN * CK; i += 256) {
        const int r = i / CK, j = i % CK;
        cand[(size_t)(b * N_ + nt0 + r) * CK + j] = ti[r][j];
    }
}

// ---------------------------------------------------------------------------
// Kernel 3: stage-2 — fp32 sequential-FMA re-rank (BLAS-order replica) + epilogue
// grid: B_*N_ = 16384 blocks, 64 threads (1 wave per row)
// ---------------------------------------------------------------------------
__launch_bounds__(64)
__global__ void raft_rerank_kernel(const float* __restrict__ f1,    // [B][C][N]
                                   const float* __restrict__ f2Tf,  // [B][N][C]
                                   const ushort* __restrict__ cand, // [B*N][CK]
                                   float* __restrict__ out) {
    __shared__ float  aS[C_];
    __shared__ float  cs[CK];
    __shared__ ushort cmS[CK];
    const int row = blockIdx.x;
    const int b   = row >> 13;
    const int n   = row & (N_ - 1);
    const int tid = threadIdx.x;       // 0..63

    if (tid < CK) cmS[tid] = cand[(size_t)row * CK + tid];
    // A-row f1[b, :, n] into LDS (strided, L2-resident)
    #pragma unroll
    for (int i = 0; i < 4; ++i) {
        const int c = tid + 64 * i;
        aS[c] = f1[((size_t)b * C_ + c) * N_ + n];
    }
    __syncthreads();

    // fp32 score, single accumulator, c ascending, strict FMA — replicates
    // BLAS sgemm per-element rounding (K=256 = one kc block, no K-split).
    if (tid < CK) {
        const int m = cmS[tid];
        const float* __restrict__ bRow = f2Tf + ((size_t)b * N_ + m) * C_;
        float acc = 0.0f;
        for (int c4 = 0; c4 < C_; c4 += 4) {
            const float4 b4 = *(const float4*)(bRow + c4);
            acc = fmaf(aS[c4 + 0], b4.x, acc);
            acc = fmaf(aS[c4 + 1], b4.y, acc);
            acc = fmaf(aS[c4 + 2], b4.z, acc);
            acc = fmaf(aS[c4 + 3], b4.w, acc);
        }
        cs[tid] = acc;
    }
    __syncthreads();

    const int y0 = n >> 7, x0 = n & 127;
    if (tid < CK) {
        const float v = cs[tid];
        const int m = cmS[tid];
        int rank = 0;
        for (int j = 0; j < CK; ++j) {
            const float vj = cs[j];
            rank += (vj > v) || ((vj == v) && (cmS[j] < m));
        }
        if (rank < K_) {
            const size_t posn = (size_t)rank * N_ + n;
            out[(size_t)b * (K_ * N_) + posn] = v * 0.0625f;   // /sqrt(256), exact
            const size_t c1b = (size_t)1572864 + (size_t)b * 2 * K_ * N_;
            out[c1b + posn]                     = (float)((m >> 7) - y0);
            out[c1b + (size_t)(K_ * N_) + posn] = (float)((m & 127) - x0);
        }
    }
    if (tid < K_) {
        const size_t posn = (size_t)tid * N_ + n;
        const size_t c0b = (size_t)524288 + (size_t)b * 2 * K_ * N_;
        out[c0b + posn]                     = (float)y0;
        out[c0b + (size_t)(K_ * N_) + posn] = (float)x0;
        out[(size_t)2621440 + (size_t)b * (K_ * N_) + posn] = (float)b;
    }
}

// ---------------------------------------------------------------------------
extern "C" void kernel_launch(void* const* d_in, const int* in_sizes, int n_in,
                              void* d_out, int out_size, void* d_ws, size_t ws_size,
                              hipStream_t stream) {
    const float* f1 = (const float*)d_in[0];   // [B][C][N] fp32
    const float* f2 = (const float*)d_in[1];

    ushort* f1T  = (ushort*)d_ws;                            // 8,388,608 B
    ushort* f2T  = f1T + (size_t)B_ * N_ * C_;               // 8,388,608 B
    float*  f2Tf = (float*)(f2T + (size_t)B_ * N_ * C_);     // 16,777,216 B
    ushort* cand = (ushort*)(f2Tf + (size_t)B_ * N_ * C_);   // 1,572,864 B

    dim3 tb(32, 8);
    dim3 tg(N_ / 32, C_ / 32, B_ * 2);
    raft_prep_kernel<<<tg, tb, 0, stream>>>(f1, f2, f1T, f2T, f2Tf);

    raft_stage1_kernel<<<dim3(B_ * (N_ / TN)), dim3(256), 0, stream>>>(f1T, f2T, cand);

    raft_rerank_kernel<<<dim3(B_ * N_), dim3(64), 0, stream>>>(f1, f2Tf, cand,
                                                               (float*)d_out);
}

// Round 6
// 675.323 us; speedup vs baseline: 17.3891x; 17.3891x over previous
//
#include <hip/hip_runtime.h>
#include <hip/hip_bf16.h>

// Problem constants (fixed by setup_inputs)
#define B_  2
#define C_  256
#define H_  64
#define W_  128
#define N_  (H_ * W_)   // 8192
#define K_  32          // top-k
#define Q_  24          // per-thread register queue depth (4 threads/row -> 96 cands)
#define CK2 96          // candidates per row handed to stage 2
#define TN  64          // n-rows per block
#define TM  64          // m-cols per tile
#define CP  264         // padded C pitch (bf16 elems)

typedef short  short8  __attribute__((ext_vector_type(8)));
typedef float  floatx4 __attribute__((ext_vector_type(4)));

// monotone fp32->uint key with candidate index packed in low 13 bits
__device__ __forceinline__ unsigned packkey(float v, int m) {
    unsigned b; __builtin_memcpy(&b, &v, 4);
    unsigned ord = (b & 0x80000000u) ? ~b : (b | 0x80000000u);
    return (ord & 0xFFFFE000u) | (unsigned)m;
}

// insert k into descending sorted register queue (no-op if k <= q[Q_-1])
__device__ __forceinline__ void qinsert(unsigned (&q)[Q_], unsigned k) {
#pragma unroll
    for (int i = Q_ - 1; i > 0; --i) {
        const unsigned prev = q[i - 1];
        q[i] = (k > q[i]) ? ((k > prev) ? prev : k) : q[i];
    }
    q[0] = (k > q[0]) ? k : q[0];
}

#define CSWAP(a, b) { const unsigned _mx = (a) > (b) ? (a) : (b); \
                      const unsigned _mn = (a) > (b) ? (b) : (a); (a) = _mx; (b) = _mn; }

// ---------------------------------------------------------------------------
// Kernel 1: prep. fp32 [B][C][N] -> bf16 [B][N][C] (both maps) + fp32 [B][N][C] (f2)
// ---------------------------------------------------------------------------
__global__ void raft_prep_kernel(const float* __restrict__ f1,
                                 const float* __restrict__ f2,
                                 ushort* __restrict__ f1T,
                                 ushort* __restrict__ f2T,
                                 float* __restrict__ f2Tf) {
    __shared__ float tile[32][33];
    const int nt = blockIdx.x;          // N/32
    const int ct = blockIdx.y;          // C/32
    const int z  = blockIdx.z;          // b*2 + which
    const int b  = z >> 1;
    const float* __restrict__ src = (z & 1) ? f2 : f1;
    ushort* __restrict__ dstB     = (z & 1) ? f2T : f1T;
    const int tx = threadIdx.x;         // 0..31
    const int ty = threadIdx.y;         // 0..7

    #pragma unroll
    for (int i = 0; i < 4; ++i) {
        const int cl = ty * 4 + i;
        tile[cl][tx] = src[((size_t)b * C_ + (ct * 32 + cl)) * N_ + (nt * 32 + tx)];
    }
    __syncthreads();
    #pragma unroll
    for (int i = 0; i < 4; ++i) {
        const int nl = ty * 4 + i;
        const float v = tile[tx][nl];
        const size_t o = ((size_t)b * N_ + (nt * 32 + nl)) * C_ + (ct * 32 + tx);
        __hip_bfloat16 h = __float2bfloat16(v);        // RNE
        dstB[o] = *(const ushort*)&h;
        if (z & 1) f2Tf[o] = v;
    }
}

// ---------------------------------------------------------------------------
// Kernel 2: stage-1 — bf16 MFMA scores GEMM + register-queue top-24x4 per row
// grid: B_*(N_/TN) = 256 blocks, 256 threads (4 waves)
// ---------------------------------------------------------------------------
__launch_bounds__(256)
__global__ void raft_stage1_kernel(const ushort* __restrict__ f1T,
                                   const ushort* __restrict__ f2T,
                                   ushort* __restrict__ cand) {
    __shared__ ushort ABl[TM][CP];      // 33,792 B: A once, then B per m-tile
    __shared__ float  Sc[TN][68];       // 17,408 B: 64x64 score tile

    const int bid  = blockIdx.x;
    const int b    = bid >> 7;
    const int nt0  = (bid & 127) * TN;
    const int tid  = threadIdx.x;
    const int w    = tid >> 6;
    const int lane = tid & 63;
    const int p    = lane & 15;
    const int q4   = lane >> 4;
    const int sr   = tid >> 2;          // scan row 0..63
    const int sj   = tid & 3;           // scan col-group 0..3

    const ushort* __restrict__ Aglob = f1T + (size_t)b * N_ * C_ + (size_t)nt0 * C_;
    const ushort* __restrict__ Bbase = f2T + (size_t)b * N_ * C_;

    // stage A tile (64 x 256)
    #pragma unroll
    for (int i = 0; i < 8; ++i) {
        const int id = tid + 256 * i;
        const int r  = id >> 5;
        const int cc = (id & 31) * 8;
        *(short8*)(&ABl[r][cc]) = *(const short8*)(Aglob + (size_t)r * C_ + cc);
    }
    __syncthreads();

    // preload A fragments
    short8 af[4][8];
    #pragma unroll
    for (int nt = 0; nt < 4; ++nt)
        #pragma unroll
        for (int ks = 0; ks < 8; ++ks)
            af[nt][ks] = *(const short8*)(&ABl[nt * 16 + p][ks * 32 + q4 * 8]);

    // per-thread candidate queue (registers)
    unsigned q[Q_];
    #pragma unroll
    for (int i = 0; i < Q_; ++i) q[i] = 0u;

    for (int mt = 0; mt < N_ / TM; ++mt) {
        const int m0 = mt * TM;
        __syncthreads();

        // stage B tile (64 x 256)
        #pragma unroll
        for (int i = 0; i < 8; ++i) {
            const int id = tid + 256 * i;
            const int r  = id >> 5;
            const int cc = (id & 31) * 8;
            *(short8*)(&ABl[r][cc]) =
                *(const short8*)(Bbase + (size_t)(m0 + r) * C_ + cc);
        }
        __syncthreads();

        // MFMA: wave w computes cols [w*16, w*16+16) for all 64 rows
        floatx4 acc[4];
        #pragma unroll
        for (int nt = 0; nt < 4; ++nt) acc[nt] = (floatx4){0.f, 0.f, 0.f, 0.f};
        #pragma unroll
        for (int ks = 0; ks < 8; ++ks) {
            const short8 bf = *(const short8*)(&ABl[w * 16 + p][ks * 32 + q4 * 8]);
            #pragma unroll
            for (int nt = 0; nt < 4; ++nt)
                acc[nt] = __builtin_amdgcn_mfma_f32_16x16x32_bf16(af[nt][ks], bf, acc[nt], 0, 0, 0);
        }
        #pragma unroll
        for (int nt = 0; nt < 4; ++nt)
            #pragma unroll
            for (int r = 0; r < 4; ++r)
                Sc[nt * 16 + q4 * 4 + r][w * 16 + p] = acc[nt][r];
        __syncthreads();

        // parallel scan: thread (sr, sj) filters 16 values of row sr
        #pragma unroll
        for (int g = 0; g < 4; ++g) {
            const floatx4 v4 = *(const floatx4*)(&Sc[sr][sj * 16 + g * 4]);
            const int mb = m0 + sj * 16 + g * 4;
            unsigned k0 = packkey(v4[0], mb + 0);
            unsigned k1 = packkey(v4[1], mb + 1);
            unsigned k2 = packkey(v4[2], mb + 2);
            unsigned k3 = packkey(v4[3], mb + 3);
            // sort4 descending
            CSWAP(k0, k1); CSWAP(k2, k3); CSWAP(k0, k2); CSWAP(k1, k3); CSWAP(k1, k2);
            qinsert(q, k0);
            if (__any(k1 > q[Q_ - 1])) {
                qinsert(q, k1);
                if (__any(k2 > q[Q_ - 1])) {
                    qinsert(q, k2);
                    if (__any(k3 > q[Q_ - 1])) qinsert(q, k3);
                }
            }
        }
    }

    // export candidate indices: row sr gets 96 = 4 threads x 24
    ushort* myc = cand + (size_t)(b * N_ + nt0 + sr) * CK2 + sj * Q_;
    #pragma unroll
    for (int t = 0; t < Q_; ++t) myc[t] = (ushort)(q[t] & 0x1FFFu);
}

// ---------------------------------------------------------------------------
// Kernel 3: stage-2 — fp32 sequential-FMA re-rank of 96 candidates + epilogue
// grid: B_*N_ = 16384 blocks, 128 threads
// ---------------------------------------------------------------------------
__launch_bounds__(128)
__global__ void raft_rerank_kernel(const float* __restrict__ f1,    // [B][C][N]
                                   const float* __restrict__ f2Tf,  // [B][N][C]
                                   const ushort* __restrict__ cand, // [B*N][CK2]
                                   float* __restrict__ out) {
    __shared__ float  aS[C_];
    __shared__ float  cs[CK2];
    __shared__ ushort cmS[CK2];
    const int row = blockIdx.x;
    const int b   = row >> 13;
    const int n   = row & (N_ - 1);
    const int tid = threadIdx.x;       // 0..127

    if (tid < CK2) cmS[tid] = cand[(size_t)row * CK2 + tid];
    // A-row f1[b, :, n] into LDS
    #pragma unroll
    for (int i = 0; i < 2; ++i) {
        const int c = tid + 128 * i;
        aS[c] = f1[((size_t)b * C_ + c) * N_ + n];
    }
    __syncthreads();

    // fp32 score, single accumulator, c ascending, strict FMA
    if (tid < CK2) {
        const int m = cmS[tid];
        const float* __restrict__ bRow = f2Tf + ((size_t)b * N_ + m) * C_;
        float acc = 0.0f;
        for (int c4 = 0; c4 < C_; c4 += 4) {
            const float4 b4 = *(const float4*)(bRow + c4);
            acc = fmaf(aS[c4 + 0], b4.x, acc);
            acc = fmaf(aS[c4 + 1], b4.y, acc);
            acc = fmaf(aS[c4 + 2], b4.z, acc);
            acc = fmaf(aS[c4 + 3], b4.w, acc);
        }
        cs[tid] = acc;
    }
    __syncthreads();

    const int y0 = n >> 7, x0 = n & 127;
    if (tid < CK2) {
        const float v = cs[tid];
        const int m = cmS[tid];
        int rank = 0;
        for (int j = 0; j < CK2; ++j) {
            const float vj = cs[j];
            rank += (vj > v) || ((vj == v) && (cmS[j] < m));
        }
        if (rank < K_) {
            const size_t posn = (size_t)rank * N_ + n;
            out[(size_t)b * (K_ * N_) + posn] = v * 0.0625f;   // /sqrt(256), exact
            const size_t c1b = (size_t)1572864 + (size_t)b * 2 * K_ * N_;
            out[c1b + posn]                     = (float)((m >> 7) - y0);
            out[c1b + (size_t)(K_ * N_) + posn] = (float)((m & 127) - x0);
        }
    }
    if (tid < K_) {
        const size_t posn = (size_t)tid * N_ + n;
        const size_t c0b = (size_t)524288 + (size_t)b * 2 * K_ * N_;
        out[c0b + posn]                     = (float)y0;
        out[c0b + (size_t)(K_ * N_) + posn] = (float)x0;
        out[(size_t)2621440 + (size_t)b * (K_ * N_) + posn] = (float)b;
    }
}

// ---------------------------------------------------------------------------
extern "C" void kernel_launch(void* const* d_in, const int* in_sizes, int n_in,
                              void* d_out, int out_size, void* d_ws, size_t ws_size,
                              hipStream_t stream) {
    const float* f1 = (const float*)d_in[0];   // [B][C][N] fp32
    const float* f2 = (const float*)d_in[1];

    ushort* f1T  = (ushort*)d_ws;                            //  8,388,608 B
    ushort* f2T  = f1T + (size_t)B_ * N_ * C_;               //  8,388,608 B
    float*  f2Tf = (float*)(f2T + (size_t)B_ * N_ * C_);     // 16,777,216 B
    ushort* cand = (ushort*)(f2Tf + (size_t)B_ * N_ * C_);   //  3,145,728 B

    dim3 tb(32, 8);
    dim3 tg(N_ / 32, C_ / 32, B_ * 2);
    raft_prep_kernel<<<tg, tb, 0, stream>>>(f1, f2, f1T, f2T, f2Tf);

    raft_stage1_kernel<<<dim3(B_ * (N_ / TN)), dim3(256), 0, stream>>>(f1T, f2T, cand);

    raft_rerank_kernel<<<dim3(B_ * N_), dim3(128), 0, stream>>>(f1, f2Tf, cand,
                                                                (float*)d_out);
}

// Round 7
// 630.451 us; speedup vs baseline: 18.6268x; 1.0712x over previous
//
#include <hip/hip_runtime.h>
#include <hip/hip_bf16.h>

// Problem constants (fixed by setup_inputs)
#define B_  2
#define C_  256
#define H_  64
#define W_  128
#define N_  (H_ * W_)   // 8192
#define K_  32          // top-k
#define Q_  24          // per-thread register queue depth (4 threads/row -> 96 cands)
#define CK2 96          // candidates per row handed to stage 2
#define TN  32          // n-rows per block
#define TM  64          // m-cols per tile
#define CP  264         // padded C pitch (bf16 elems)

typedef short  short8  __attribute__((ext_vector_type(8)));
typedef float  floatx4 __attribute__((ext_vector_type(4)));

__device__ __forceinline__ unsigned umin_(unsigned a, unsigned b) { return a < b ? a : b; }
__device__ __forceinline__ unsigned umax_(unsigned a, unsigned b) { return a > b ? a : b; }

// key: top-19 bits of fp32 (clamped to >=0, monotone) | 13-bit index.
// Top-96 scores are always >> 0, so clamping negatives to 0 is lossless.
__device__ __forceinline__ unsigned packkey(float v, int m) {
    const float vc = v > 0.0f ? v : 0.0f;
    unsigned b; __builtin_memcpy(&b, &vc, 4);
    return (b & 0xFFFFE000u) | (unsigned)m;
}

// descending-sorted register queue insert: q[i] = med3(q[i-1], k, q[i])
__device__ __forceinline__ void qinsert(unsigned (&q)[Q_], unsigned k) {
#pragma unroll
    for (int i = Q_ - 1; i > 0; --i)
        q[i] = umax_(umin_(q[i - 1], k), q[i]);   // v_med3_u32
    q[0] = umax_(q[0], k);
}

#define CSWAP(a, b) { const unsigned _mx = umax_(a, b); \
                      const unsigned _mn = umin_(a, b); (a) = _mx; (b) = _mn; }

// ---------------------------------------------------------------------------
// Kernel 1: prep. fp32 [B][C][N] -> bf16 [B][N][C] (both maps) + fp32 [B][N][C] (f2)
// ---------------------------------------------------------------------------
__global__ void raft_prep_kernel(const float* __restrict__ f1,
                                 const float* __restrict__ f2,
                                 ushort* __restrict__ f1T,
                                 ushort* __restrict__ f2T,
                                 float* __restrict__ f2Tf) {
    __shared__ float tile[32][33];
    const int nt = blockIdx.x;          // N/32
    const int ct = blockIdx.y;          // C/32
    const int z  = blockIdx.z;          // b*2 + which
    const int b  = z >> 1;
    const float* __restrict__ src = (z & 1) ? f2 : f1;
    ushort* __restrict__ dstB     = (z & 1) ? f2T : f1T;
    const int tx = threadIdx.x;         // 0..31
    const int ty = threadIdx.y;         // 0..7

    #pragma unroll
    for (int i = 0; i < 4; ++i) {
        const int cl = ty * 4 + i;
        tile[cl][tx] = src[((size_t)b * C_ + (ct * 32 + cl)) * N_ + (nt * 32 + tx)];
    }
    __syncthreads();
    #pragma unroll
    for (int i = 0; i < 4; ++i) {
        const int nl = ty * 4 + i;
        const float v = tile[tx][nl];
        const size_t o = ((size_t)b * N_ + (nt * 32 + nl)) * C_ + (ct * 32 + tx);
        __hip_bfloat16 h = __float2bfloat16(v);        // RNE
        dstB[o] = *(const ushort*)&h;
        if (z & 1) f2Tf[o] = v;
    }
}

// ---------------------------------------------------------------------------
// Kernel 2: stage-1 — bf16 MFMA scores GEMM + med3 register-queue top-24x4/row
// grid: B_*(N_/TN) = 512 blocks (2/CU), 128 threads (2 waves)
// ---------------------------------------------------------------------------
__launch_bounds__(128)
__global__ void raft_stage1_kernel(const ushort* __restrict__ f1T,
                                   const ushort* __restrict__ f2T,
                                   ushort* __restrict__ cand) {
    __shared__ ushort ABl[TM][CP];      // 33,792 B: A (32 rows) once, then B per m-tile
    __shared__ float  Sc[TN][68];       //  8,704 B: 32x64 score tile

    const int bid  = blockIdx.x;
    const int b    = bid >> 8;                   // / 256
    const int nt0  = (bid & 255) * TN;
    const int tid  = threadIdx.x;                // 0..127
    const int w    = tid >> 6;                   // wave 0..1
    const int lane = tid & 63;
    const int p    = lane & 15;
    const int q4   = lane >> 4;
    const int sr   = tid >> 2;                   // scan row 0..31
    const int sj   = tid & 3;                    // scan col-group 0..3

    const ushort* __restrict__ Aglob = f1T + (size_t)b * N_ * C_ + (size_t)nt0 * C_;
    const ushort* __restrict__ Bbase = f2T + (size_t)b * N_ * C_;

    // stage A tile (32 rows x 256 c)
    #pragma unroll
    for (int i = 0; i < 8; ++i) {
        const int id = tid + 128 * i;            // 0..1023
        const int r  = id >> 5;
        const int cc = (id & 31) * 8;
        *(short8*)(&ABl[r][cc]) = *(const short8*)(Aglob + (size_t)r * C_ + cc);
    }
    __syncthreads();

    // preload A fragments: af[nt][ks], 2x8 short8 = 64 VGPR
    short8 af[2][8];
    #pragma unroll
    for (int nt = 0; nt < 2; ++nt)
        #pragma unroll
        for (int ks = 0; ks < 8; ++ks)
            af[nt][ks] = *(const short8*)(&ABl[nt * 16 + p][ks * 32 + q4 * 8]);

    unsigned q[Q_];
    #pragma unroll
    for (int i = 0; i < Q_; ++i) q[i] = 0u;

    for (int mt = 0; mt < N_ / TM; ++mt) {
        const int m0 = mt * TM;
        __syncthreads();

        // stage B tile (64 rows x 256 c)
        #pragma unroll
        for (int i = 0; i < 16; ++i) {
            const int id = tid + 128 * i;        // 0..2047
            const int r  = id >> 5;
            const int cc = (id & 31) * 8;
            *(short8*)(&ABl[r][cc]) =
                *(const short8*)(Bbase + (size_t)(m0 + r) * C_ + cc);
        }
        __syncthreads();

        // MFMA: wave w computes cols [w*32, w*32+32) for rows 0..31
        floatx4 acc[2][2];
        #pragma unroll
        for (int nt = 0; nt < 2; ++nt)
            #pragma unroll
            for (int cf = 0; cf < 2; ++cf) acc[nt][cf] = (floatx4){0.f, 0.f, 0.f, 0.f};
        #pragma unroll
        for (int ks = 0; ks < 8; ++ks) {
            #pragma unroll
            for (int cf = 0; cf < 2; ++cf) {
                const short8 bf = *(const short8*)(&ABl[w * 32 + cf * 16 + p][ks * 32 + q4 * 8]);
                #pragma unroll
                for (int nt = 0; nt < 2; ++nt)
                    acc[nt][cf] = __builtin_amdgcn_mfma_f32_16x16x32_bf16(af[nt][ks], bf, acc[nt][cf], 0, 0, 0);
            }
        }
        #pragma unroll
        for (int nt = 0; nt < 2; ++nt)
            #pragma unroll
            for (int cf = 0; cf < 2; ++cf)
                #pragma unroll
                for (int r = 0; r < 4; ++r)
                    Sc[nt * 16 + q4 * 4 + r][w * 32 + cf * 16 + p] = acc[nt][cf][r];
        __syncthreads();

        // parallel scan: thread (sr, sj) filters 16 values of row sr
        #pragma unroll
        for (int g = 0; g < 4; ++g) {
            const floatx4 v4 = *(const floatx4*)(&Sc[sr][sj * 16 + g * 4]);
            const int mb = m0 + sj * 16 + g * 4;
            unsigned k0 = packkey(v4[0], mb + 0);
            unsigned k1 = packkey(v4[1], mb + 1);
            unsigned k2 = packkey(v4[2], mb + 2);
            unsigned k3 = packkey(v4[3], mb + 3);
            // sort4 descending (min/max network)
            CSWAP(k0, k1); CSWAP(k2, k3); CSWAP(k0, k2); CSWAP(k1, k3); CSWAP(k1, k2);
            qinsert(q, k0);
            if (__any(k1 > q[Q_ - 1])) {
                qinsert(q, k1);
                if (__any(k2 > q[Q_ - 1])) {
                    qinsert(q, k2);
                    if (__any(k3 > q[Q_ - 1])) qinsert(q, k3);
                }
            }
        }
    }

    // export candidate indices: row sr gets 96 = 4 threads x 24
    ushort* myc = cand + (size_t)(b * N_ + nt0 + sr) * CK2 + sj * Q_;
    #pragma unroll
    for (int t = 0; t < Q_; ++t) myc[t] = (ushort)(q[t] & 0x1FFFu);
}

// ---------------------------------------------------------------------------
// Kernel 3: stage-2 — fp32 sequential-FMA re-rank of 96 candidates + epilogue
// grid: B_*N_ = 16384 blocks, 128 threads
// ---------------------------------------------------------------------------
__launch_bounds__(128)
__global__ void raft_rerank_kernel(const float* __restrict__ f1,    // [B][C][N]
                                   const float* __restrict__ f2Tf,  // [B][N][C]
                                   const ushort* __restrict__ cand, // [B*N][CK2]
                                   float* __restrict__ out) {
    __shared__ float  aS[C_];
    __shared__ float  cs[CK2];
    __shared__ ushort cmS[CK2];
    const int row = blockIdx.x;
    const int b   = row >> 13;
    const int n   = row & (N_ - 1);
    const int tid = threadIdx.x;       // 0..127

    if (tid < CK2) cmS[tid] = cand[(size_t)row * CK2 + tid];
    // A-row f1[b, :, n] into LDS
    #pragma unroll
    for (int i = 0; i < 2; ++i) {
        const int c = tid + 128 * i;
        aS[c] = f1[((size_t)b * C_ + c) * N_ + n];
    }
    __syncthreads();

    // fp32 score, single accumulator, c ascending, strict FMA
    if (tid < CK2) {
        const int m = cmS[tid];
        const float* __restrict__ bRow = f2Tf + ((size_t)b * N_ + m) * C_;
        float acc = 0.0f;
        for (int c4 = 0; c4 < C_; c4 += 4) {
            const float4 b4 = *(const float4*)(bRow + c4);
            acc = fmaf(aS[c4 + 0], b4.x, acc);
            acc = fmaf(aS[c4 + 1], b4.y, acc);
            acc = fmaf(aS[c4 + 2], b4.z, acc);
            acc = fmaf(aS[c4 + 3], b4.w, acc);
        }
        cs[tid] = acc;
    }
    __syncthreads();

    const int y0 = n >> 7, x0 = n & 127;
    if (tid < CK2) {
        const float v = cs[tid];
        const int m = cmS[tid];
        int rank = 0;
        for (int j = 0; j < CK2; ++j) {
            const float vj = cs[j];
            rank += (vj > v) || ((vj == v) && (cmS[j] < m));
        }
        if (rank < K_) {
            const size_t posn = (size_t)rank * N_ + n;
            out[(size_t)b * (K_ * N_) + posn] = v * 0.0625f;   // /sqrt(256), exact
            const size_t c1b = (size_t)1572864 + (size_t)b * 2 * K_ * N_;
            out[c1b + posn]                     = (float)((m >> 7) - y0);
            out[c1b + (size_t)(K_ * N_) + posn] = (float)((m & 127) - x0);
        }
    }
    if (tid < K_) {
        const size_t posn = (size_t)tid * N_ + n;
        const size_t c0b = (size_t)524288 + (size_t)b * 2 * K_ * N_;
        out[c0b + posn]                     = (float)y0;
        out[c0b + (size_t)(K_ * N_) + posn] = (float)x0;
        out[(size_t)2621440 + (size_t)b * (K_ * N_) + posn] = (float)b;
    }
}

// ---------------------------------------------------------------------------
extern "C" void kernel_launch(void* const* d_in, const int* in_sizes, int n_in,
                              void* d_out, int out_size, void* d_ws, size_t ws_size,
                              hipStream_t stream) {
    const float* f1 = (const float*)d_in[0];   // [B][C][N] fp32
    const float* f2 = (const float*)d_in[1];

    ushort* f1T  = (ushort*)d_ws;                            //  8,388,608 B
    ushort* f2T  = f1T + (size_t)B_ * N_ * C_;               //  8,388,608 B
    float*  f2Tf = (float*)(f2T + (size_t)B_ * N_ * C_);     // 16,777,216 B
    ushort* cand = (ushort*)(f2Tf + (size_t)B_ * N_ * C_);   //  3,145,728 B

    dim3 tb(32, 8);
    dim3 tg(N_ / 32, C_ / 32, B_ * 2);
    raft_prep_kernel<<<tg, tb, 0, stream>>>(f1, f2, f1T, f2T, f2Tf);

    raft_stage1_kernel<<<dim3(B_ * (N_ / TN)), dim3(128), 0, stream>>>(f1T, f2T, cand);

    raft_rerank_kernel<<<dim3(B_ * N_), dim3(128), 0, stream>>>(f1, f2Tf, cand,
                                                                (float*)d_out);
}

// Round 8
// 504.346 us; speedup vs baseline: 23.2842x; 1.2500x over previous
//
#include <hip/hip_runtime.h>
#include <hip/hip_bf16.h>

// Problem constants (fixed by setup_inputs)
#define B_  2
#define C_  256
#define H_  64
#define W_  128
#define N_  (H_ * W_)   // 8192
#define K_  32          // top-k
#define Q_  24          // per-lane register queue depth (4 q4-streams/row -> 96 cands)
#define CK2 96          // candidates per row handed to stage 2
#define TN  64          // n-rows per block
#define TM  64          // m-cols per tile
#define NT_ (N_ / TM)   // 128 m-tiles

typedef short  short8  __attribute__((ext_vector_type(8)));
typedef float  floatx4 __attribute__((ext_vector_type(4)));

__device__ __forceinline__ unsigned umin_(unsigned a, unsigned b) { return a < b ? a : b; }
__device__ __forceinline__ unsigned umax_(unsigned a, unsigned b) { return a > b ? a : b; }
__device__ __forceinline__ ushort f2bf(float v) {
    __hip_bfloat16 h = __float2bfloat16(v);   // RNE
    ushort u; __builtin_memcpy(&u, &h, 2); return u;
}

// key: top-19 bits of fp32 (clamped >=0, monotone) | 13-bit m index
__device__ __forceinline__ unsigned packkey(float v, int m) {
    const float vc = v > 0.0f ? v : 0.0f;
    unsigned b; __builtin_memcpy(&b, &vc, 4);
    return (b & 0xFFFFE000u) | (unsigned)m;
}

// descending-sorted register queue insert: q[i] = med3(q[i-1], k, q[i])
__device__ __forceinline__ void qinsert(unsigned (&q)[Q_], unsigned k) {
#pragma unroll
    for (int i = Q_ - 1; i > 0; --i)
        q[i] = umax_(umin_(q[i - 1], k), q[i]);   // v_med3_u32
    q[0] = umax_(q[0], k);
}

#define CSWAP(a, b) { const unsigned _mx = umax_(a, b); \
                      const unsigned _mn = umin_(a, b); (a) = _mx; (b) = _mn; }

// ---------------------------------------------------------------------------
// Kernel 1: prep. fp32 [B][C][N] -> f1Tf fp32 [B][N][C], f2T bf16 [B][N][C],
//           f2Tf fp32 [B][N][C]
// ---------------------------------------------------------------------------
__global__ void raft_prep_kernel(const float* __restrict__ f1,
                                 const float* __restrict__ f2,
                                 float* __restrict__ f1Tf,
                                 ushort* __restrict__ f2T,
                                 float* __restrict__ f2Tf) {
    __shared__ float tile[32][33];
    const int nt = blockIdx.x;          // N/32
    const int ct = blockIdx.y;          // C/32
    const int z  = blockIdx.z;          // b*2 + which
    const int b  = z >> 1;
    const float* __restrict__ src = (z & 1) ? f2 : f1;
    const int tx = threadIdx.x;         // 0..31
    const int ty = threadIdx.y;         // 0..7

    #pragma unroll
    for (int i = 0; i < 4; ++i) {
        const int cl = ty * 4 + i;
        tile[cl][tx] = src[((size_t)b * C_ + (ct * 32 + cl)) * N_ + (nt * 32 + tx)];
    }
    __syncthreads();
    #pragma unroll
    for (int i = 0; i < 4; ++i) {
        const int nl = ty * 4 + i;
        const float v = tile[tx][nl];
        const size_t o = ((size_t)b * N_ + (nt * 32 + nl)) * C_ + (ct * 32 + tx);
        if (z & 1) {
            f2Tf[o] = v;
            f2T[o]  = f2bf(v);
        } else {
            f1Tf[o] = v;
        }
    }
}

// ---------------------------------------------------------------------------
// Kernel 2: stage-1 — S^T MFMA (A=f2,B=f1) + in-register per-lane top-24
// grid: B_*(N_/TN) = 256 blocks, 256 threads (4 waves). One barrier/tile.
// Double-buffered B-tile, XOR-swizzled (CP=256), 64 KB LDS.
// ---------------------------------------------------------------------------
__launch_bounds__(256)
__global__ void raft_stage1_kernel(const float* __restrict__ f1Tf,
                                   const ushort* __restrict__ f2T,
                                   ushort* __restrict__ cand) {
    __shared__ ushort Bt[2][TM * 256];   // 65,536 B

    const int bid  = blockIdx.x;
    const int b    = bid >> 7;
    const int nt0  = (bid & 127) * TN;
    const int tid  = threadIdx.x;
    const int w    = tid >> 6;                   // wave 0..3 -> n-strip
    const int lane = tid & 63;
    const int p    = lane & 15;
    const int q4   = lane >> 4;
    const int nrow = nt0 + w * 16 + p;           // this lane's n-row

    // ---- f1 fragments (B-operand): fp32 -> bf16 RNE, 8 x short8 ----
    short8 af[8];
    {
        const float* __restrict__ arow = f1Tf + ((size_t)b * N_ + nrow) * C_;
        #pragma unroll
        for (int ks = 0; ks < 8; ++ks) {
            const float4 x = *(const float4*)(arow + ks * 32 + q4 * 8);
            const float4 y = *(const float4*)(arow + ks * 32 + q4 * 8 + 4);
            short8 t;
            t[0] = f2bf(x.x); t[1] = f2bf(x.y); t[2] = f2bf(x.z); t[3] = f2bf(x.w);
            t[4] = f2bf(y.x); t[5] = f2bf(y.y); t[6] = f2bf(y.z); t[7] = f2bf(y.w);
            af[ks] = t;
        }
    }

    unsigned q[Q_];
    #pragma unroll
    for (int i = 0; i < Q_; ++i) q[i] = 0u;

    const ushort* __restrict__ Bbase = f2T + (size_t)b * N_ * C_;

    // ---- stage m-tile 0 into Bt[0] (swizzled) ----
    #pragma unroll
    for (int i = 0; i < 8; ++i) {
        const int idx = tid + 256 * i;           // 0..2047
        const int r   = idx >> 5;                // tile row (m)
        const int c8  = idx & 31;                // 16B chunk
        const short8 v = *(const short8*)(Bbase + (size_t)r * C_ + c8 * 8);
        *(short8*)(&Bt[0][(r * 32 + (c8 ^ (r & 7))) * 8]) = v;
    }
    __syncthreads();

    for (int mt = 0; mt < NT_; ++mt) {
        const int m0 = mt * TM;
        const ushort* __restrict__ cur = Bt[mt & 1];
        ushort* __restrict__ nxt       = Bt[(mt & 1) ^ 1];

        // issue next-tile global loads (fly across MFMA + filter)
        short8 stg[8];
        if (mt < NT_ - 1) {
            #pragma unroll
            for (int i = 0; i < 8; ++i) {
                const int idx = tid + 256 * i;
                const int r   = idx >> 5;
                const int c8  = idx & 31;
                stg[i] = *(const short8*)(Bbase + (size_t)(m0 + TM + r) * C_ + c8 * 8);
            }
        }

        // ---- MFMA: acc[f][r] = S^T[m = m0 + f*16 + q4*4 + r][n = nrow] ----
        floatx4 acc[4];
        #pragma unroll
        for (int f = 0; f < 4; ++f) acc[f] = (floatx4){0.f, 0.f, 0.f, 0.f};
        #pragma unroll
        for (int ks = 0; ks < 8; ++ks) {
            #pragma unroll
            for (int f = 0; f < 4; ++f) {
                const short8 bm = *(const short8*)(
                    &cur[((f * 16 + p) * 32 + ((ks * 4 + q4) ^ (p & 7))) * 8]);
                acc[f] = __builtin_amdgcn_mfma_f32_16x16x32_bf16(bm, af[ks], acc[f], 0, 0, 0);
            }
        }

        // ---- in-register filter: 4 groups of 4 consecutive m ----
        #pragma unroll
        for (int f = 0; f < 4; ++f) {
            const int mb = m0 + f * 16 + q4 * 4;
            unsigned k0 = packkey(acc[f][0], mb + 0);
            unsigned k1 = packkey(acc[f][1], mb + 1);
            unsigned k2 = packkey(acc[f][2], mb + 2);
            unsigned k3 = packkey(acc[f][3], mb + 3);
            CSWAP(k0, k1); CSWAP(k2, k3); CSWAP(k0, k2); CSWAP(k1, k3); CSWAP(k1, k2);
            qinsert(q, k0);
            if (__any(k1 > q[Q_ - 1])) {
                qinsert(q, k1);
                if (__any(k2 > q[Q_ - 1])) {
                    qinsert(q, k2);
                    if (__any(k3 > q[Q_ - 1])) qinsert(q, k3);
                }
            }
        }

        // ---- commit staged tile to LDS, single barrier ----
        if (mt < NT_ - 1) {
            #pragma unroll
            for (int i = 0; i < 8; ++i) {
                const int idx = tid + 256 * i;
                const int r   = idx >> 5;
                const int c8  = idx & 31;
                *(short8*)(&nxt[(r * 32 + (c8 ^ (r & 7))) * 8]) = stg[i];
            }
        }
        __syncthreads();
    }

    // export candidate indices: row nrow, slice q4
    ushort* myc = cand + ((size_t)(b * N_ + nrow)) * CK2 + q4 * Q_;
    #pragma unroll
    for (int t = 0; t < Q_; ++t) myc[t] = (ushort)(q[t] & 0x1FFFu);
}

// ---------------------------------------------------------------------------
// Kernel 3: stage-2 — fp32 sequential-FMA re-rank of 96 candidates + epilogue
// grid: B_*N_ = 16384 blocks, 128 threads
// ---------------------------------------------------------------------------
__launch_bounds__(128)
__global__ void raft_rerank_kernel(const float* __restrict__ f1Tf,  // [B][N][C]
                                   const float* __restrict__ f2Tf,  // [B][N][C]
                                   const ushort* __restrict__ cand, // [B*N][CK2]
                                   float* __restrict__ out) {
    __shared__ float  aS[C_];
    __shared__ float  cs[CK2];
    __shared__ ushort cmS[CK2];
    const int row = blockIdx.x;
    const int b   = row >> 13;
    const int n   = row & (N_ - 1);
    const int tid = threadIdx.x;       // 0..127

    if (tid < CK2) cmS[tid] = cand[(size_t)row * CK2 + tid];
    // A-row f1Tf[b][n][:] -> LDS, contiguous coalesced
    if (tid < 64)
        *(float4*)(&aS[tid * 4]) = *(const float4*)(f1Tf + ((size_t)b * N_ + n) * C_ + tid * 4);
    __syncthreads();

    // fp32 score, single accumulator, c ascending, strict FMA
    if (tid < CK2) {
        const int m = cmS[tid];
        const float* __restrict__ bRow = f2Tf + ((size_t)b * N_ + m) * C_;
        float acc = 0.0f;
        for (int c4 = 0; c4 < C_; c4 += 4) {
            const float4 b4 = *(const float4*)(bRow + c4);
            acc = fmaf(aS[c4 + 0], b4.x, acc);
            acc = fmaf(aS[c4 + 1], b4.y, acc);
            acc = fmaf(aS[c4 + 2], b4.z, acc);
            acc = fmaf(aS[c4 + 3], b4.w, acc);
        }
        cs[tid] = acc;
    }
    __syncthreads();

    const int y0 = n >> 7, x0 = n & 127;
    if (tid < CK2) {
        const float v = cs[tid];
        const int m = cmS[tid];
        int rank = 0;
        for (int j = 0; j < CK2; ++j) {
            const float vj = cs[j];
            rank += (vj > v) || ((vj == v) && (cmS[j] < m));
        }
        if (rank < K_) {
            const size_t posn = (size_t)rank * N_ + n;
            out[(size_t)b * (K_ * N_) + posn] = v * 0.0625f;   // /sqrt(256), exact
            const size_t c1b = (size_t)1572864 + (size_t)b * 2 * K_ * N_;
            out[c1b + posn]                     = (float)((m >> 7) - y0);
            out[c1b + (size_t)(K_ * N_) + posn] = (float)((m & 127) - x0);
        }
    }
    if (tid < K_) {
        const size_t posn = (size_t)tid * N_ + n;
        const size_t c0b = (size_t)524288 + (size_t)b * 2 * K_ * N_;
        out[c0b + posn]                     = (float)y0;
        out[c0b + (size_t)(K_ * N_) + posn] = (float)x0;
        out[(size_t)2621440 + (size_t)b * (K_ * N_) + posn] = (float)b;
    }
}

// ---------------------------------------------------------------------------
extern "C" void kernel_launch(void* const* d_in, const int* in_sizes, int n_in,
                              void* d_out, int out_size, void* d_ws, size_t ws_size,
                              hipStream_t stream) {
    const float* f1 = (const float*)d_in[0];   // [B][C][N] fp32
    const float* f2 = (const float*)d_in[1];

    float*  f1Tf = (float*)d_ws;                             // 16,777,216 B
    float*  f2Tf = f1Tf + (size_t)B_ * N_ * C_;              // 16,777,216 B
    ushort* f2T  = (ushort*)(f2Tf + (size_t)B_ * N_ * C_);   //  8,388,608 B
    ushort* cand = f2T + (size_t)B_ * N_ * C_;               //  3,145,728 B

    dim3 tb(32, 8);
    dim3 tg(N_ / 32, C_ / 32, B_ * 2);
    raft_prep_kernel<<<tg, tb, 0, stream>>>(f1, f2, f1Tf, f2T, f2Tf);

    raft_stage1_kernel<<<dim3(B_ * (N_ / TN)), dim3(256), 0, stream>>>(f1Tf, f2T, cand);

    raft_rerank_kernel<<<dim3(B_ * N_), dim3(128), 0, stream>>>(f1Tf, f2Tf, cand,
                                                                (float*)d_out);
}

// Round 9
// 494.338 us; speedup vs baseline: 23.7556x; 1.0202x over previous
//
#include <hip/hip_runtime.h>
#include <hip/hip_bf16.h>

// Problem constants (fixed by setup_inputs)
#define B_  2
#define C_  256
#define H_  64
#define W_  128
#define N_  (H_ * W_)   // 8192
#define K_  32          // top-k
#define Q_  24          // per-lane register queue depth
#define CK2 96          // candidates per row handed to stage 2
#define TN  32          // n-rows per block (2 strips x 16)
#define TM  64          // m-rows per half-tile
#define NHT 64          // tiles per m-half (4096/64)

typedef short  short8  __attribute__((ext_vector_type(8)));
typedef short  short4v __attribute__((ext_vector_type(4)));
typedef float  floatx4 __attribute__((ext_vector_type(4)));

__device__ __forceinline__ unsigned umin_(unsigned a, unsigned b) { return a < b ? a : b; }
__device__ __forceinline__ unsigned umax_(unsigned a, unsigned b) { return a > b ? a : b; }
__device__ __forceinline__ ushort f2bf(float v) {
    __hip_bfloat16 h = __float2bfloat16(v);   // RNE
    ushort u; __builtin_memcpy(&u, &h, 2); return u;
}

// key: top-19 bits of fp32 (clamped >=0, monotone) | 13-bit m index
__device__ __forceinline__ unsigned packkey(float v, int m) {
    const float vc = v > 0.0f ? v : 0.0f;
    unsigned b; __builtin_memcpy(&b, &vc, 4);
    return (b & 0xFFFFE000u) | (unsigned)m;
}

// descending-sorted register queue insert: q[i] = med3(q[i-1], k, q[i])
__device__ __forceinline__ void qinsert(unsigned (&q)[Q_], unsigned k) {
#pragma unroll
    for (int i = Q_ - 1; i > 0; --i)
        q[i] = umax_(umin_(q[i - 1], k), q[i]);   // v_med3_u32
    q[0] = umax_(q[0], k);
}

#define CSWAP(a, b) { const unsigned _mx = umax_(a, b); \
                      const unsigned _mn = umin_(a, b); (a) = _mx; (b) = _mn; }

// ---------------------------------------------------------------------------
// Kernel 1: prep (vectorized). fp32 [B][C][N] -> f1Tf fp32 [B][N][C],
//           f2Tf fp32 [B][N][C], f2T bf16 [B][N][C]
// grid (N/32, C/32, B*2), 256 threads
// ---------------------------------------------------------------------------
__global__ void raft_prep_kernel(const float* __restrict__ f1,
                                 const float* __restrict__ f2,
                                 float* __restrict__ f1Tf,
                                 ushort* __restrict__ f2T,
                                 float* __restrict__ f2Tf) {
    __shared__ float tile[32][33];
    const int nt = blockIdx.x;
    const int ct = blockIdx.y;
    const int z  = blockIdx.z;          // b*2 + which
    const int b  = z >> 1;
    const float* __restrict__ src = (z & 1) ? f2 : f1;
    const int tid = threadIdx.x;

    // read: 32 c-rows x 32 n (float4 along n, coalesced)
    {
        const int cl = tid >> 3;        // 0..31
        const int nx = tid & 7;         // 0..7 (x4 n)
        const float4 v = *(const float4*)(
            src + ((size_t)b * C_ + (ct * 32 + cl)) * N_ + (nt * 32 + nx * 4));
        tile[cl][nx * 4 + 0] = v.x;
        tile[cl][nx * 4 + 1] = v.y;
        tile[cl][nx * 4 + 2] = v.z;
        tile[cl][nx * 4 + 3] = v.w;
    }
    __syncthreads();

    // write: 32 n-rows x 32 c (float4 along c, coalesced)
    {
        const int nl = tid >> 3;        // 0..31
        const int c4 = (tid & 7) * 4;   // 0,4,..28
        float4 v;
        v.x = tile[c4 + 0][nl];
        v.y = tile[c4 + 1][nl];
        v.z = tile[c4 + 2][nl];
        v.w = tile[c4 + 3][nl];
        const size_t o = ((size_t)b * N_ + (nt * 32 + nl)) * C_ + (ct * 32 + c4);
        if (z & 1) {
            *(float4*)(f2Tf + o) = v;
            short4v h;
            h[0] = (short)f2bf(v.x); h[1] = (short)f2bf(v.y);
            h[2] = (short)f2bf(v.z); h[3] = (short)f2bf(v.w);
            *(short4v*)(f2T + o) = h;
        } else {
            *(float4*)(f1Tf + o) = v;
        }
    }
}

// ---------------------------------------------------------------------------
// Kernel 2: stage-1 — S^T MFMA + in-register top-24, m-split across 2 halves.
// grid: B_*(N_/TN) = 512 blocks (2/CU), 256 threads = 4 waves:
//   wave w: n-strip s = w>>1 (16 rows), m-half h = w&1 (4096 m).
// LDS: 2 single-buffered half-tiles (64 KB). Register prefetch across MFMA.
// End: per-(n,q4) merge of the two sorted half-queues -> top-24 (set identical
// to the round-8 full-m queue).
// ---------------------------------------------------------------------------
__launch_bounds__(256, 2)
__global__ void raft_stage1_kernel(const float* __restrict__ f1Tf,
                                   const ushort* __restrict__ f2T,
                                   ushort* __restrict__ cand) {
    __shared__ ushort Bt[2][TM * 256];   // 65,536 B: [half][64x256]

    const int bid  = blockIdx.x;
    const int b    = bid >> 8;                   // grid 512
    const int nt0  = (bid & 255) * TN;
    const int tid  = threadIdx.x;
    const int w    = tid >> 6;                   // 0..3
    const int s    = w >> 1;                     // n-strip 0..1
    const int h    = w & 1;                      // m-half 0..1
    const int lane = tid & 63;
    const int p    = lane & 15;
    const int q4   = lane >> 4;
    const int nrow = nt0 + s * 16 + p;
    const int mbase = h * (N_ / 2);
    const int lt   = s * 64 + lane;              // 0..127 within half-group

    // ---- f1 fragments (B-operand): fp32 -> bf16 RNE, 8 x short8 ----
    short8 af[8];
    {
        const float* __restrict__ arow = f1Tf + ((size_t)b * N_ + nrow) * C_;
        #pragma unroll
        for (int ks = 0; ks < 8; ++ks) {
            const float4 x = *(const float4*)(arow + ks * 32 + q4 * 8);
            const float4 y = *(const float4*)(arow + ks * 32 + q4 * 8 + 4);
            short8 t;
            t[0] = (short)f2bf(x.x); t[1] = (short)f2bf(x.y);
            t[2] = (short)f2bf(x.z); t[3] = (short)f2bf(x.w);
            t[4] = (short)f2bf(y.x); t[5] = (short)f2bf(y.y);
            t[6] = (short)f2bf(y.z); t[7] = (short)f2bf(y.w);
            af[ks] = t;
        }
    }

    unsigned q[Q_];
    #pragma unroll
    for (int i = 0; i < Q_; ++i) q[i] = 0u;

    const ushort* __restrict__ Bb = f2T + (size_t)b * N_ * C_ + (size_t)mbase * C_;

    // ---- preload tile 0 of this half into registers ----
    short8 stg[16];
    #pragma unroll
    for (int i = 0; i < 16; ++i) {
        const int idx = lt + 128 * i;            // 0..2047
        const int r   = idx >> 5;
        const int c8  = idx & 31;
        stg[i] = *(const short8*)(Bb + (size_t)r * C_ + c8 * 8);
    }

    for (int mt = 0; mt < NHT; ++mt) {
        // ---- commit staged tile to LDS (swizzled) ----
        {
            ushort* __restrict__ dst = Bt[h];
            #pragma unroll
            for (int i = 0; i < 16; ++i) {
                const int idx = lt + 128 * i;
                const int r   = idx >> 5;
                const int c8  = idx & 31;
                *(short8*)(&dst[(r * 32 + (c8 ^ (r & 7))) * 8]) = stg[i];
            }
        }
        __syncthreads();

        // ---- issue next-tile global loads (fly across MFMA + filter) ----
        if (mt < NHT - 1) {
            const ushort* __restrict__ src = Bb + (size_t)(mt + 1) * TM * C_;
            #pragma unroll
            for (int i = 0; i < 16; ++i) {
                const int idx = lt + 128 * i;
                const int r   = idx >> 5;
                const int c8  = idx & 31;
                stg[i] = *(const short8*)(src + (size_t)r * C_ + c8 * 8);
            }
        }

        // ---- MFMA: acc[f][r] = S^T[m = m0 + f*16 + q4*4 + r][n = nrow] ----
        const ushort* __restrict__ cur = Bt[h];
        floatx4 acc[4];
        #pragma unroll
        for (int f = 0; f < 4; ++f) acc[f] = (floatx4){0.f, 0.f, 0.f, 0.f};
        #pragma unroll
        for (int ks = 0; ks < 8; ++ks) {
            #pragma unroll
            for (int f = 0; f < 4; ++f) {
                const short8 bm = *(const short8*)(
                    &cur[((f * 16 + p) * 32 + ((ks * 4 + q4) ^ (p & 7))) * 8]);
                acc[f] = __builtin_amdgcn_mfma_f32_16x16x32_bf16(bm, af[ks], acc[f], 0, 0, 0);
            }
        }

        // ---- in-register filter ----
        const int m0 = mbase + mt * TM;
        #pragma unroll
        for (int f = 0; f < 4; ++f) {
            const int mb = m0 + f * 16 + q4 * 4;
            unsigned k0 = packkey(acc[f][0], mb + 0);
            unsigned k1 = packkey(acc[f][1], mb + 1);
            unsigned k2 = packkey(acc[f][2], mb + 2);
            unsigned k3 = packkey(acc[f][3], mb + 3);
            CSWAP(k0, k1); CSWAP(k2, k3); CSWAP(k0, k2); CSWAP(k1, k3); CSWAP(k1, k2);
            qinsert(q, k0);
            if (__any(k1 > q[Q_ - 1])) {
                qinsert(q, k1);
                if (__any(k2 > q[Q_ - 1])) {
                    qinsert(q, k2);
                    if (__any(k3 > q[Q_ - 1])) qinsert(q, k3);
                }
            }
        }
        __syncthreads();   // all reads done before next commit / merge reuse
    }

    // ---- merge halves per (n,q4): top-24 of two sorted-desc 24-lists ----
    unsigned* __restrict__ mg = (unsigned*)&Bt[0][0];   // 128 pairs x 48 keys = 24,576 B
    const int pairidx = (s * 16 + p) * 4 + q4;          // 0..127
    #pragma unroll
    for (int t = 0; t < Q_; ++t) mg[pairidx * 48 + h * 24 + t] = q[t];
    __syncthreads();

    if (tid < 128) {
        const unsigned* __restrict__ A  = &mg[tid * 48];
        const unsigned* __restrict__ Bq = A + 24;
        const int nl = tid >> 2, qq = tid & 3;
        ushort* __restrict__ myc = cand + ((size_t)(b * N_ + nt0 + nl)) * CK2 + qq * 24;
        int i = 0, j = 0;
        #pragma unroll
        for (int t = 0; t < 24; ++t) {
            const unsigned a = A[i], bb = Bq[j];
            if (a >= bb) { myc[t] = (ushort)(a  & 0x1FFFu); ++i; }
            else         { myc[t] = (ushort)(bb & 0x1FFFu); ++j; }
        }
    }
}

// ---------------------------------------------------------------------------
// Kernel 3: stage-2 — fp32 sequential-FMA re-rank of 96 candidates + epilogue
// grid: B_*N_ = 16384 blocks, 128 threads
// ---------------------------------------------------------------------------
__launch_bounds__(128)
__global__ void raft_rerank_kernel(const float* __restrict__ f1Tf,  // [B][N][C]
                                   const float* __restrict__ f2Tf,  // [B][N][C]
                                   const ushort* __restrict__ cand, // [B*N][CK2]
                                   float* __restrict__ out) {
    __shared__ float  aS[C_];
    __shared__ float  cs[CK2];
    __shared__ ushort cmS[CK2];
    const int row = blockIdx.x;
    const int b   = row >> 13;
    const int n   = row & (N_ - 1);
    const int tid = threadIdx.x;       // 0..127

    if (tid < CK2) cmS[tid] = cand[(size_t)row * CK2 + tid];
    if (tid < 64)
        *(float4*)(&aS[tid * 4]) = *(const float4*)(f1Tf + ((size_t)b * N_ + n) * C_ + tid * 4);
    __syncthreads();

    // fp32 score, single accumulator, c ascending, strict FMA
    if (tid < CK2) {
        const int m = cmS[tid];
        const float* __restrict__ bRow = f2Tf + ((size_t)b * N_ + m) * C_;
        float acc = 0.0f;
        for (int c4 = 0; c4 < C_; c4 += 4) {
            const float4 b4 = *(const float4*)(bRow + c4);
            acc = fmaf(aS[c4 + 0], b4.x, acc);
            acc = fmaf(aS[c4 + 1], b4.y, acc);
            acc = fmaf(aS[c4 + 2], b4.z, acc);
            acc = fmaf(aS[c4 + 3], b4.w, acc);
        }
        cs[tid] = acc;
    }
    __syncthreads();

    const int y0 = n >> 7, x0 = n & 127;
    if (tid < CK2) {
        const float v = cs[tid];
        const int m = cmS[tid];
        int rank = 0;
        for (int j = 0; j < CK2; ++j) {
            const float vj = cs[j];
            rank += (vj > v) || ((vj == v) && (cmS[j] < m));
        }
        if (rank < K_) {
            const size_t posn = (size_t)rank * N_ + n;
            out[(size_t)b * (K_ * N_) + posn] = v * 0.0625f;   // /sqrt(256), exact
            const size_t c1b = (size_t)1572864 + (size_t)b * 2 * K_ * N_;
            out[c1b + posn]                     = (float)((m >> 7) - y0);
            out[c1b + (size_t)(K_ * N_) + posn] = (float)((m & 127) - x0);
        }
    }
    if (tid < K_) {
        const size_t posn = (size_t)tid * N_ + n;
        const size_t c0b = (size_t)524288 + (size_t)b * 2 * K_ * N_;
        out[c0b + posn]                     = (float)y0;
        out[c0b + (size_t)(K_ * N_) + posn] = (float)x0;
        out[(size_t)2621440 + (size_t)b * (K_ * N_) + posn] = (float)b;
    }
}

// ---------------------------------------------------------------------------
extern "C" void kernel_launch(void* const* d_in, const int* in_sizes, int n_in,
                              void* d_out, int out_size, void* d_ws, size_t ws_size,
                              hipStream_t stream) {
    const float* f1 = (const float*)d_in[0];   // [B][C][N] fp32
    const float* f2 = (const float*)d_in[1];

    float*  f1Tf = (float*)d_ws;                             // 16,777,216 B
    float*  f2Tf = f1Tf + (size_t)B_ * N_ * C_;              // 16,777,216 B
    ushort* f2T  = (ushort*)(f2Tf + (size_t)B_ * N_ * C_);   //  8,388,608 B
    ushort* cand = f2T + (size_t)B_ * N_ * C_;               //  3,145,728 B

    raft_prep_kernel<<<dim3(N_ / 32, C_ / 32, B_ * 2), dim3(256), 0, stream>>>(
        f1, f2, f1Tf, f2T, f2Tf);

    raft_stage1_kernel<<<dim3(B_ * (N_ / TN)), dim3(256), 0, stream>>>(f1Tf, f2T, cand);

    raft_rerank_kernel<<<dim3(B_ * N_), dim3(128), 0, stream>>>(f1Tf, f2Tf, cand,
                                                                (float*)d_out);
}

// Round 10
// 395.942 us; speedup vs baseline: 29.6591x; 1.2485x over previous
//
#include <hip/hip_runtime.h>
#include <hip/hip_bf16.h>

// Problem constants (fixed by setup_inputs)
#define B_  2
#define C_  256
#define H_  64
#define W_  128
#define N_  (H_ * W_)   // 8192
#define K_  32          // top-k
#define Q_  24          // per-lane register queue depth
#define CK2 48          // candidates per row handed to stage 2 (bf16-sorted)
#define TN  32          // n-rows per block (2 strips x 16)
#define TM  64          // m-rows per half-tile
#define NHT 64          // tiles per m-half (4096/64)

typedef short  short8  __attribute__((ext_vector_type(8)));
typedef short  short4v __attribute__((ext_vector_type(4)));
typedef float  floatx4 __attribute__((ext_vector_type(4)));

__device__ __forceinline__ unsigned umin_(unsigned a, unsigned b) { return a < b ? a : b; }
__device__ __forceinline__ unsigned umax_(unsigned a, unsigned b) { return a > b ? a : b; }
__device__ __forceinline__ ushort f2bf(float v) {
    __hip_bfloat16 h = __float2bfloat16(v);   // RNE
    ushort u; __builtin_memcpy(&u, &h, 2); return u;
}
// hardware median-of-3 (valid as shift-insert because q[i] <= q[i-1])
__device__ __forceinline__ unsigned med3u(unsigned a, unsigned b, unsigned c) {
    unsigned d;
    asm("v_med3_u32 %0, %1, %2, %3" : "=v"(d) : "v"(a), "v"(b), "v"(c));
    return d;
}

// key: top-19 bits of fp32 (clamped >=0, monotone) | 13-bit m index
__device__ __forceinline__ unsigned packkey(float v, int m) {
    const float vc = v > 0.0f ? v : 0.0f;
    unsigned b; __builtin_memcpy(&b, &vc, 4);
    return (b & 0xFFFFE000u) | (unsigned)m;
}

// descending-sorted register queue insert via v_med3_u32
__device__ __forceinline__ void qinsert(unsigned (&q)[Q_], unsigned k) {
#pragma unroll
    for (int i = Q_ - 1; i > 0; --i)
        q[i] = med3u(q[i - 1], k, q[i]);
    q[0] = umax_(q[0], k);
}

#define CSWAP(a, b) { const unsigned _mx = umax_(a, b); \
                      const unsigned _mn = umin_(a, b); (a) = _mx; (b) = _mn; }

// ---------------------------------------------------------------------------
// Kernel 1: prep (vectorized). fp32 [B][C][N] -> f1Tf fp32 [B][N][C],
//           f2Tf fp32 [B][N][C], f2T bf16 [B][N][C]
// ---------------------------------------------------------------------------
__global__ void raft_prep_kernel(const float* __restrict__ f1,
                                 const float* __restrict__ f2,
                                 float* __restrict__ f1Tf,
                                 ushort* __restrict__ f2T,
                                 float* __restrict__ f2Tf) {
    __shared__ float tile[32][33];
    const int nt = blockIdx.x;
    const int ct = blockIdx.y;
    const int z  = blockIdx.z;          // b*2 + which
    const int b  = z >> 1;
    const float* __restrict__ src = (z & 1) ? f2 : f1;
    const int tid = threadIdx.x;

    {
        const int cl = tid >> 3;        // 0..31
        const int nx = tid & 7;         // 0..7 (x4 n)
        const float4 v = *(const float4*)(
            src + ((size_t)b * C_ + (ct * 32 + cl)) * N_ + (nt * 32 + nx * 4));
        tile[cl][nx * 4 + 0] = v.x;
        tile[cl][nx * 4 + 1] = v.y;
        tile[cl][nx * 4 + 2] = v.z;
        tile[cl][nx * 4 + 3] = v.w;
    }
    __syncthreads();
    {
        const int nl = tid >> 3;        // 0..31
        const int c4 = (tid & 7) * 4;   // 0,4,..28
        float4 v;
        v.x = tile[c4 + 0][nl];
        v.y = tile[c4 + 1][nl];
        v.z = tile[c4 + 2][nl];
        v.w = tile[c4 + 3][nl];
        const size_t o = ((size_t)b * N_ + (nt * 32 + nl)) * C_ + (ct * 32 + c4);
        if (z & 1) {
            *(float4*)(f2Tf + o) = v;
            short4v h;
            h[0] = (short)f2bf(v.x); h[1] = (short)f2bf(v.y);
            h[2] = (short)f2bf(v.z); h[3] = (short)f2bf(v.w);
            *(short4v*)(f2T + o) = h;
        } else {
            *(float4*)(f1Tf + o) = v;
        }
    }
}

// ---------------------------------------------------------------------------
// Kernel 2: stage-1 — S^T MFMA + med3 register top-24 (m-split), then LDS
// merge of the 8 per-(slice,half) queues into one bf16-sorted top-48 per row.
// grid: 512 blocks (2/CU), 256 threads = 4 waves (2 n-strips x 2 m-halves).
// ---------------------------------------------------------------------------
__launch_bounds__(256, 2)
__global__ void raft_stage1_kernel(const float* __restrict__ f1Tf,
                                   const ushort* __restrict__ f2T,
                                   ushort* __restrict__ cand) {
    __shared__ ushort Bt[2][TM * 256];   // 65,536 B: [half][64x256]

    const int bid  = blockIdx.x;
    const int b    = bid >> 8;                   // grid 512
    const int nt0  = (bid & 255) * TN;
    const int tid  = threadIdx.x;
    const int w    = tid >> 6;                   // 0..3
    const int s    = w >> 1;                     // n-strip 0..1
    const int h    = w & 1;                      // m-half 0..1
    const int lane = tid & 63;
    const int p    = lane & 15;
    const int q4   = lane >> 4;
    const int nrow = nt0 + s * 16 + p;
    const int mbase = h * (N_ / 2);
    const int lt   = s * 64 + lane;              // 0..127 within half-group

    // ---- f1 fragments (B-operand): fp32 -> bf16 RNE, 8 x short8 ----
    short8 af[8];
    {
        const float* __restrict__ arow = f1Tf + ((size_t)b * N_ + nrow) * C_;
        #pragma unroll
        for (int ks = 0; ks < 8; ++ks) {
            const float4 x = *(const float4*)(arow + ks * 32 + q4 * 8);
            const float4 y = *(const float4*)(arow + ks * 32 + q4 * 8 + 4);
            short8 t;
            t[0] = (short)f2bf(x.x); t[1] = (short)f2bf(x.y);
            t[2] = (short)f2bf(x.z); t[3] = (short)f2bf(x.w);
            t[4] = (short)f2bf(y.x); t[5] = (short)f2bf(y.y);
            t[6] = (short)f2bf(y.z); t[7] = (short)f2bf(y.w);
            af[ks] = t;
        }
    }

    unsigned q[Q_];
    #pragma unroll
    for (int i = 0; i < Q_; ++i) q[i] = 0u;

    const ushort* __restrict__ Bb = f2T + (size_t)b * N_ * C_ + (size_t)mbase * C_;

    // ---- preload tile 0 of this half into registers ----
    short8 stg[16];
    #pragma unroll
    for (int i = 0; i < 16; ++i) {
        const int idx = lt + 128 * i;            // 0..2047
        const int r   = idx >> 5;
        const int c8  = idx & 31;
        stg[i] = *(const short8*)(Bb + (size_t)r * C_ + c8 * 8);
    }

    for (int mt = 0; mt < NHT; ++mt) {
        // ---- commit staged tile to LDS (swizzled) ----
        {
            ushort* __restrict__ dst = Bt[h];
            #pragma unroll
            for (int i = 0; i < 16; ++i) {
                const int idx = lt + 128 * i;
                const int r   = idx >> 5;
                const int c8  = idx & 31;
                *(short8*)(&dst[(r * 32 + (c8 ^ (r & 7))) * 8]) = stg[i];
            }
        }
        __syncthreads();

        // ---- issue next-tile global loads (fly across MFMA + filter) ----
        if (mt < NHT - 1) {
            const ushort* __restrict__ src = Bb + (size_t)(mt + 1) * TM * C_;
            #pragma unroll
            for (int i = 0; i < 16; ++i) {
                const int idx = lt + 128 * i;
                const int r   = idx >> 5;
                const int c8  = idx & 31;
                stg[i] = *(const short8*)(src + (size_t)r * C_ + c8 * 8);
            }
        }

        // ---- MFMA: acc[f][r] = S^T[m = m0 + f*16 + q4*4 + r][n = nrow] ----
        const ushort* __restrict__ cur = Bt[h];
        floatx4 acc[4];
        #pragma unroll
        for (int f = 0; f < 4; ++f) acc[f] = (floatx4){0.f, 0.f, 0.f, 0.f};
        #pragma unroll
        for (int ks = 0; ks < 8; ++ks) {
            #pragma unroll
            for (int f = 0; f < 4; ++f) {
                const short8 bm = *(const short8*)(
                    &cur[((f * 16 + p) * 32 + ((ks * 4 + q4) ^ (p & 7))) * 8]);
                acc[f] = __builtin_amdgcn_mfma_f32_16x16x32_bf16(bm, af[ks], acc[f], 0, 0, 0);
            }
        }

        // ---- in-register filter ----
        const int m0 = mbase + mt * TM;
        #pragma unroll
        for (int f = 0; f < 4; ++f) {
            const int mb = m0 + f * 16 + q4 * 4;
            unsigned k0 = packkey(acc[f][0], mb + 0);
            unsigned k1 = packkey(acc[f][1], mb + 1);
            unsigned k2 = packkey(acc[f][2], mb + 2);
            unsigned k3 = packkey(acc[f][3], mb + 3);
            CSWAP(k0, k1); CSWAP(k2, k3); CSWAP(k0, k2); CSWAP(k1, k3); CSWAP(k1, k2);
            qinsert(q, k0);
            if (__any(k1 > q[Q_ - 1])) {
                qinsert(q, k1);
                if (__any(k2 > q[Q_ - 1])) {
                    qinsert(q, k2);
                    if (__any(k3 > q[Q_ - 1])) qinsert(q, k3);
                }
            }
        }
        __syncthreads();   // all reads done before next commit
    }

    // ---- tail: merge 8 sorted-24 lists per row -> bf16-sorted top-48 ----
    // mg[row][slice][half][24] : 32*4*2*24 = 6144 u32 (24 KB)
    unsigned* __restrict__ mg = (unsigned*)&Bt[0][0];
    const int rowl = s * 16 + p;
    #pragma unroll
    for (int t = 0; t < Q_; ++t)
        mg[((rowl * 4 + q4) * 2 + h) * Q_ + t] = q[t];
    __syncthreads();

    // stage A: 128 threads: (row, slice) merge half0+half1 -> sorted 48
    unsigned* __restrict__ ms = mg + 6144;       // 32*4*48 = 6144 u32 (24 KB)
    if (tid < 128) {
        const int r  = tid >> 2, sl = tid & 3;
        const unsigned* __restrict__ A  = &mg[((r * 4 + sl) * 2 + 0) * Q_];
        const unsigned* __restrict__ Bq = &mg[((r * 4 + sl) * 2 + 1) * Q_];
        unsigned* __restrict__ O = &ms[(r * 4 + sl) * 48];
        int i = 0, j = 0;
        for (int t = 0; t < 48; ++t) {
            const unsigned a  = A[i];            // i,j <= t < 48, always valid reads
            const unsigned bb = Bq[j];
            const bool ta = (i < 24) && (j >= 24 || a >= bb);
            O[t] = ta ? a : bb;
            i += ta; j += !ta;
        }
    }
    __syncthreads();

    // stage B: 32 threads: 4-way merge, take first 48, emit indices
    if (tid < 32) {
        const unsigned* __restrict__ L = &ms[tid * 4 * 48];
        int i0 = 0, i1 = 0, i2 = 0, i3 = 0;
        ushort* __restrict__ myc = cand + ((size_t)(b * N_ + nt0 + tid)) * CK2;
        for (int t = 0; t < 48; ++t) {
            const unsigned a0 = L[i0], a1 = L[48 + i1], a2 = L[96 + i2], a3 = L[144 + i3];
            const unsigned m01 = umax_(a0, a1), m23 = umax_(a2, a3);
            const unsigned mx  = umax_(m01, m23);
            myc[t] = (ushort)(mx & 0x1FFFu);
            i0 += (a0 == mx);
            i1 += (a0 != mx) & (a1 == mx);
            i2 += (a0 != mx) & (a1 != mx) & (a2 == mx);
            i3 += (a0 != mx) & (a1 != mx) & (a2 != mx) & (a3 == mx);
        }
    }
}

// ---------------------------------------------------------------------------
// Kernel 3: stage-2 — fp32 sequential-FMA re-rank of 48 candidates + epilogue
// grid: B_*N_ = 16384 blocks, 64 threads
// ---------------------------------------------------------------------------
__launch_bounds__(64)
__global__ void raft_rerank_kernel(const float* __restrict__ f1Tf,  // [B][N][C]
                                   const float* __restrict__ f2Tf,  // [B][N][C]
                                   const ushort* __restrict__ cand, // [B*N][CK2]
                                   float* __restrict__ out) {
    __shared__ float  aS[C_];
    __shared__ float  cs[CK2];
    __shared__ ushort cmS[CK2];
    const int row = blockIdx.x;
    const int b   = row >> 13;
    const int n   = row & (N_ - 1);
    const int tid = threadIdx.x;       // 0..63

    if (tid < CK2) cmS[tid] = cand[(size_t)row * CK2 + tid];
    *(float4*)(&aS[tid * 4]) = *(const float4*)(f1Tf + ((size_t)b * N_ + n) * C_ + tid * 4);
    __syncthreads();

    // fp32 score, single accumulator, c ascending, strict FMA
    if (tid < CK2) {
        const int m = cmS[tid];
        const float* __restrict__ bRow = f2Tf + ((size_t)b * N_ + m) * C_;
        float acc = 0.0f;
        for (int c4 = 0; c4 < C_; c4 += 4) {
            const float4 b4 = *(const float4*)(bRow + c4);
            acc = fmaf(aS[c4 + 0], b4.x, acc);
            acc = fmaf(aS[c4 + 1], b4.y, acc);
            acc = fmaf(aS[c4 + 2], b4.z, acc);
            acc = fmaf(aS[c4 + 3], b4.w, acc);
        }
        cs[tid] = acc;
    }
    __syncthreads();

    const int y0 = n >> 7, x0 = n & 127;
    if (tid < CK2) {
        const float v = cs[tid];
        const int m = cmS[tid];
        int rank = 0;
        for (int j = 0; j < CK2; ++j) {
            const float vj = cs[j];
            rank += (vj > v) || ((vj == v) && (cmS[j] < m));
        }
        if (rank < K_) {
            const size_t posn = (size_t)rank * N_ + n;
            out[(size_t)b * (K_ * N_) + posn] = v * 0.0625f;   // /sqrt(256), exact
            const size_t c1b = (size_t)1572864 + (size_t)b * 2 * K_ * N_;
            out[c1b + posn]                     = (float)((m >> 7) - y0);
            out[c1b + (size_t)(K_ * N_) + posn] = (float)((m & 127) - x0);
        }
    }
    if (tid < K_) {
        const size_t posn = (size_t)tid * N_ + n;
        const size_t c0b = (size_t)524288 + (size_t)b * 2 * K_ * N_;
        out[c0b + posn]                     = (float)y0;
        out[c0b + (size_t)(K_ * N_) + posn] = (float)x0;
        out[(size_t)2621440 + (size_t)b * (K_ * N_) + posn] = (float)b;
    }
}

// ---------------------------------------------------------------------------
extern "C" void kernel_launch(void* const* d_in, const int* in_sizes, int n_in,
                              void* d_out, int out_size, void* d_ws, size_t ws_size,
                              hipStream_t stream) {
    const float* f1 = (const float*)d_in[0];   // [B][C][N] fp32
    const float* f2 = (const float*)d_in[1];

    float*  f1Tf = (float*)d_ws;                             // 16,777,216 B
    float*  f2Tf = f1Tf + (size_t)B_ * N_ * C_;              // 16,777,216 B
    ushort* f2T  = (ushort*)(f2Tf + (size_t)B_ * N_ * C_);   //  8,388,608 B
    ushort* cand = f2T + (size_t)B_ * N_ * C_;               //  1,572,864 B

    raft_prep_kernel<<<dim3(N_ / 32, C_ / 32, B_ * 2), dim3(256), 0, stream>>>(
        f1, f2, f1Tf, f2T, f2Tf);

    raft_stage1_kernel<<<dim3(B_ * (N_ / TN)), dim3(256), 0, stream>>>(f1Tf, f2T, cand);

    raft_rerank_kernel<<<dim3(B_ * N_), dim3(64), 0, stream>>>(f1Tf, f2Tf, cand,
                                                               (float*)d_out);
}